// Round 2
// baseline (113.984 us; speedup 1.0000x reference)
//
#include <hip/hip_runtime.h>

#define HW    4096
#define CDIM  64
#define KCB   1024
#define NELM  8388608
#define NBLK  256          // one 1024-thread block per CU

typedef __attribute__((ext_vector_type(8))) short  short8;
typedef __attribute__((ext_vector_type(4))) float  float4v;

__device__ inline unsigned short f2bf(float v) {
    unsigned u = __builtin_bit_cast(unsigned, v);
    unsigned r = u + 0x7FFF + ((u >> 16) & 1);   // RNE
    return (unsigned short)(r >> 16);
}
__device__ inline unsigned umin32(unsigned a, unsigned b) { return a < b ? a : b; }

// ws: [0..1023] e_sq+1.0 fp32 | [1024] loss accum | [1025] ticket | [2048..] bf16 -2*cb (B-frag order)
__global__ void vq_prep(const float* __restrict__ cb, float* __restrict__ esqb,
                        float* __restrict__ accum, int* __restrict__ cnt,
                        unsigned short* __restrict__ cbB) {
    int u = blockIdx.x * 256 + threadIdx.x;      // 0..8191
    if (u == 0) { *accum = 0.0f; *cnt = 0; }
    if (u < KCB) {
        const float* row = cb + u * CDIM;
        float s = 0.0f;
        #pragma unroll
        for (int c = 0; c < CDIM; ++c) s = fmaf(row[c], row[c], s);
        esqb[u] = s + 1.0f;                      // +1 bias => packed distances strictly positive
    }
    // B-frag order (R2/R4/R5/R6-verified). B carries -2*e; A carries raw x.
    int k = u >> 3, s7 = u & 7;
    const float* src = cb + k * CDIM + s7 * 8;
    unsigned short tmp[8];
    #pragma unroll
    for (int j = 0; j < 8; ++j) tmp[j] = f2bf(-2.0f * src[j]);
    int kt = k >> 4, n = k & 15, f = s7 >> 2, q = s7 & 3;
    int dst = (((kt * 2 + f) * 64) + q * 16 + n) * 8;
    *(short8*)(cbB + dst) = *(short8*)tmp;
}

__global__ __launch_bounds__(1024, 4)   // 16 waves/CU, VGPR cap 128
void vq_main(const float* __restrict__ x,
             const float* __restrict__ cb,
             const float* __restrict__ esqb,
             const unsigned short* __restrict__ cbB,
             float* __restrict__ zq,
             float* __restrict__ accum,
             int* __restrict__ cnt,
             float* __restrict__ loss_out) {
    // Overlay: bbuf (128 KB, k-loop) and zbuf (64*513*4 = 128.25 KB, epilogue) share smem.
    __shared__ __align__(16) unsigned char smem[131328];
    __shared__ float lesq[KCB];      // 4 KB
    __shared__ int   idxl[512];      // 2 KB
    __shared__ float wred[16];
    unsigned short* bbuf = (unsigned short*)smem;
    float*          zbuf = (float*)smem;         // [c*513 + pt], stride 513 -> conflict-free

    const int t   = threadIdx.x;                 // 0..1023, 16 waves
    const int n0  = blockIdx.x * 512;            // 512 points per block
    const int b   = n0 >> 12;
    const int hw0 = n0 & (HW - 1);
    const int l   = t & 63, w = t >> 6;
    const int col = l & 15, q = l >> 4;
    const int p0  = w * 32;                      // wave's 32 points

    // ---- stage codebook into LDS: 8 rounds x 1024 threads x 16 B ----
    #pragma unroll
    for (int i = 0; i < 8; ++i) {
        int off = (i * 1024 + t) * 8;            // shorts
        __builtin_amdgcn_global_load_lds(
            (const __attribute__((address_space(1))) unsigned int*)(cbB + off),
            (__attribute__((address_space(3))) unsigned int*)(&bbuf[off]),
            16, 0, 0);
    }
    lesq[t] = esqb[t];

    // ---- A fragments direct from global (overlaps staging): 32 pts/wave ----
    short8 a[2][2];
    float  xs = 0.0f;
    const float* xbase = x + (size_t)b * CDIM * HW + hw0;
    #pragma unroll
    for (int mt = 0; mt < 2; ++mt) {
        const int p = p0 + mt * 16 + col;
        #pragma unroll
        for (int f = 0; f < 2; ++f) {
            unsigned short tmp[8];
            #pragma unroll
            for (int j = 0; j < 8; ++j) {
                float v = xbase[(size_t)(f * 32 + q * 8 + j) * HW + p];
                xs = fmaf(v, v, xs);
                tmp[j] = f2bf(v);
            }
            a[mt][f] = *(short8*)tmp;
        }
    }
    __syncthreads();   // bbuf + lesq resident

    // ---- k-loop: B from LDS; acc = (1+e_sq) + x·(-2e); packed argmin ----
    unsigned bm[8];
    #pragma unroll
    for (int i = 0; i < 8; ++i) bm[i] = 0xFFFFFFFFu;
    unsigned cand = (unsigned)col;
    const short8* bl = ((const short8*)bbuf) + l;

    auto kt_body = [&](int kt, short8 b0, short8 b1) {
        float ev = lesq[kt * 16 + col];
        float4v c0 = {ev, ev, ev, ev};
        #pragma unroll
        for (int mt = 0; mt < 2; ++mt) {
            float4v acc = __builtin_amdgcn_mfma_f32_16x16x32_bf16(a[mt][0], b0, c0, 0, 0, 0);
            acc = __builtin_amdgcn_mfma_f32_16x16x32_bf16(a[mt][1], b1, acc, 0, 0, 0);
            #pragma unroll
            for (int r = 0; r < 4; ++r) {
                unsigned pk = (__builtin_bit_cast(unsigned, acc[r]) & 0xFFFFFC00u) | cand;
                bm[mt * 4 + r] = umin32(bm[mt * 4 + r], pk);
            }
        }
        cand += 16;
    };

    short8 A0 = bl[0],   A1 = bl[64];
    short8 A2 = bl[128], A3 = bl[192];
    for (int kt = 0; kt < 64; kt += 2) {
        short8 t0 = A0, t1 = A1, t2 = A2, t3 = A3;
        if (kt + 2 < 64) {
            A0 = bl[(kt + 2) * 128];  A1 = bl[(kt + 2) * 128 + 64];
            A2 = bl[(kt + 3) * 128];  A3 = bl[(kt + 3) * 128 + 64];
        }
        kt_body(kt,     t0, t1);
        kt_body(kt + 1, t2, t3);
    }

    // ---- argmin across the 16 code-columns (packed butterfly) ----
    #pragma unroll
    for (int s = 1; s < 16; s <<= 1)
        #pragma unroll
        for (int i = 0; i < 8; ++i) {
            unsigned o = (unsigned)__shfl_xor((int)bm[i], s, 64);
            bm[i] = umin32(bm[i], o);
        }

    // publish indices: point = p0 + mt*16 + q*4 + r
    if (col == 0) {
        #pragma unroll
        for (int mt = 0; mt < 2; ++mt)
            #pragma unroll
            for (int r = 0; r < 4; ++r)
                idxl[p0 + mt * 16 + q * 4 + r] = (int)(bm[mt * 4 + r] & 1023u);
    }

    // ---- loss partial: Σ x_sq + Σ best(e_sq - 2 dot) over wave's 32 pts ----
    {
        float dsum = 0.0f;
        #pragma unroll
        for (int i = 0; i < 8; ++i)
            dsum += __builtin_bit_cast(float, bm[i] & 0xFFFFFC00u);
        float lp = xs + dsum * 0.0625f - 0.5f;   // /16 col-replication; un-bias 32 pts / 64 lanes
        #pragma unroll
        for (int off = 32; off > 0; off >>= 1) lp += __shfl_down(lp, off, 64);
        if (l == 0) wred[w] = lp;
    }
    __syncthreads();   // bbuf dead, idxl + wred ready

    if (t == 0) {
        float s = 0.0f;
        #pragma unroll
        for (int i = 0; i < 16; ++i) s += wred[i];
        atomicAdd(accum, s);
    }

    // ---- phase 1: cooperative gather of winning rows -> zbuf (channel-major) ----
    #pragma unroll
    for (int i = 0; i < 8; ++i) {
        int g  = i * 1024 + t;                   // float4 unit: 512 pts x 16
        int pt = g >> 4, sg = g & 15;
        const float4v vv = *(const float4v*)(cb + (size_t)idxl[pt] * CDIM + sg * 4);
        #pragma unroll
        for (int j = 0; j < 4; ++j) zbuf[(sg * 4 + j) * 513 + pt] = vv[j];
    }
    __syncthreads();   // zbuf ready

    // ---- phase 2: coalesced z_q stores from zbuf ----
    {
        const int pt = t & 511, ch = t >> 9;     // 32 channels per thread
        float* zp = zq + ((size_t)b * CDIM + ch * 32) * HW + hw0 + pt;
        #pragma unroll
        for (int c = 0; c < 32; ++c)
            zp[(size_t)c * HW] = zbuf[(ch * 32 + c) * 513 + pt];
    }

    // ---- fused final: last block writes the loss ----
    if (t == 0) {
        __threadfence();
        int tk = atomicAdd(cnt, 1);
        if (tk == NBLK - 1) {
            float tot = atomicAdd(accum, 0.0f);
            loss_out[0] = 1.25f * tot * (1.0f / (float)NELM);
        }
    }
}

extern "C" void kernel_launch(void* const* d_in, const int* in_sizes, int n_in,
                              void* d_out, int out_size, void* d_ws, size_t ws_size,
                              hipStream_t stream) {
    const float* x  = (const float*)d_in[0];
    const float* cb = (const float*)d_in[1];
    float* esqb  = (float*)d_ws;
    float* accum = esqb + KCB;
    int*   cnt   = (int*)(esqb + KCB + 1);
    unsigned short* cbB = (unsigned short*)(esqb + 2048);
    float* zq   = (float*)d_out;
    float* loss = zq + NELM;

    vq_prep <<<32,   256,  0, stream>>>(cb, esqb, accum, cnt, cbB);
    vq_main <<<NBLK, 1024, 0, stream>>>(x, cb, esqb, cbB, zq, accum, cnt, loss);
}